// Round 1
// baseline (517.346 us; speedup 1.0000x reference)
//
#include <hip/hip_runtime.h>
#include <math.h>

#define N_NODES 50000
#define N_EDGES 800000
#define HD 128          // H*D = 4*32
#define GG 1024
#define NEG_SLOPE 0.2f
#define SCAN_B 1024
#define NB ((N_NODES + SCAN_B - 1) / SCAN_B)   // 49

typedef __attribute__((ext_vector_type(8))) short bf16x8;
typedef __attribute__((ext_vector_type(4))) float f32x4;

__device__ __forceinline__ unsigned short f2bf(float v) {
    unsigned u = __float_as_uint(v);
    u += 0x7fff + ((u >> 16) & 1);       // round-to-nearest-even
    return (unsigned short)(u >> 16);
}
__device__ __forceinline__ float bf2f(unsigned short s) {
    return __uint_as_float((unsigned)s << 16);
}

// --------------------------------------------------- split-bf16 conversions
__global__ void convert_x(const float* __restrict__ x, unsigned short* __restrict__ Xh,
                          unsigned short* __restrict__ Xl, int total)
{
    int i = blockIdx.x * 256 + threadIdx.x;
    if (i >= total) return;
    float v = x[i];
    unsigned short hi = f2bf(v);
    unsigned short lo = f2bf(v - bf2f(hi));   // residual is exact in fp32
    Xh[i] = hi; Xl[i] = lo;
}

// W (K x 128) pair -> Wt (256 x K) transposed, split hi/lo. rows 0..127 = Wl cols.
__global__ void convert_w(const float* __restrict__ Wl, const float* __restrict__ Wr,
                          unsigned short* __restrict__ Wth, unsigned short* __restrict__ Wtl,
                          int K)
{
    int t = blockIdx.x * 256 + threadIdx.x;
    if (t >= 256 * K) return;
    int c = t / K, k = t - c * K;
    float v = (c < 128) ? Wl[(size_t)k * 128 + c] : Wr[(size_t)k * 128 + (c - 128)];
    unsigned short hi = f2bf(v);
    unsigned short lo = f2bf(v - bf2f(hi));
    Wth[t] = hi; Wtl[t] = lo;
}

// --------------------------------------------------- MFMA split-bf16 dual GEMM
// Cl[n,128]=X@Wl+bl ; Cr[n,128]=X@Wr+br. X given as bf16 hi/lo row-major [n][K],
// W given transposed [256][K] bf16 hi/lo. Block: 64 rows x 256 cols, 4 waves,
// wave-tile 64x64 (4x4 of 16x16x32), 3 MFMA per tile-pair (hh, hl, lh).
template<int K>
__launch_bounds__(256)
__global__ void gemm_mfma(const unsigned short* __restrict__ Xh, const unsigned short* __restrict__ Xl,
                          const unsigned short* __restrict__ Wth, const unsigned short* __restrict__ Wtl,
                          const float* __restrict__ bl, const float* __restrict__ br,
                          float* __restrict__ Cl, float* __restrict__ Cr, int n)
{
    constexpr int KC = 32;
    constexpr int NCH = K / KC;
    constexpr int XR = 40;                     // LDS row stride (elems): 80 B -> 2-way max
    __shared__ unsigned short XsH[64 * XR], XsL[64 * XR];     // 5.12 KB each
    __shared__ unsigned short WsH[256 * XR], WsL[256 * XR];   // 20.5 KB each
    const int tid  = threadIdx.x;
    const int wave = tid >> 6;
    const int lane = tid & 63;
    const int quad = lane >> 4;
    const int l15  = lane & 15;
    const int row0 = blockIdx.x * 64;

    f32x4 acc[4][4];                           // [mt][nt]
    #pragma unroll
    for (int i = 0; i < 4; i++)
        #pragma unroll
        for (int j = 0; j < 4; j++) acc[i][j] = (f32x4){0.f, 0.f, 0.f, 0.f};

    for (int ch = 0; ch < NCH; ch++) {
        const int k0 = ch * KC;
        // stage X chunk: 64 rows x 32 k (1 uint4 per thread per buffer)
        {
            const int r = tid >> 2, seg = tid & 3;
            const int row = row0 + r;
            const size_t go = (size_t)row * K + k0 + seg * 8;
            uint4 vh = make_uint4(0, 0, 0, 0), vl = make_uint4(0, 0, 0, 0);
            if (row < n) { vh = *(const uint4*)(Xh + go); vl = *(const uint4*)(Xl + go); }
            *(uint4*)&XsH[r * XR + seg * 8] = vh;
            *(uint4*)&XsL[r * XR + seg * 8] = vl;
        }
        // stage W chunk: 256 rows x 32 k (4 uint4 per thread per buffer)
        #pragma unroll
        for (int i = 0; i < 4; i++) {
            const int f = tid + i * 256;
            const int wr = f >> 2, seg = f & 3;
            const size_t go = (size_t)wr * K + k0 + seg * 8;
            *(uint4*)&WsH[wr * XR + seg * 8] = *(const uint4*)(Wth + go);
            *(uint4*)&WsL[wr * XR + seg * 8] = *(const uint4*)(Wtl + go);
        }
        __syncthreads();

        bf16x8 ah[4], al[4];
        #pragma unroll
        for (int mt = 0; mt < 4; mt++) {
            ah[mt] = *(const bf16x8*)&XsH[(mt * 16 + l15) * XR + quad * 8];
            al[mt] = *(const bf16x8*)&XsL[(mt * 16 + l15) * XR + quad * 8];
        }
        #pragma unroll
        for (int nt = 0; nt < 4; nt++) {
            const int wr = wave * 64 + nt * 16 + l15;
            const bf16x8 bh = *(const bf16x8*)&WsH[wr * XR + quad * 8];
            const bf16x8 bo = *(const bf16x8*)&WsL[wr * XR + quad * 8];
            #pragma unroll
            for (int mt = 0; mt < 4; mt++) {
                acc[mt][nt] = __builtin_amdgcn_mfma_f32_16x16x32_bf16(ah[mt], bh, acc[mt][nt], 0, 0, 0);
                acc[mt][nt] = __builtin_amdgcn_mfma_f32_16x16x32_bf16(ah[mt], bo, acc[mt][nt], 0, 0, 0);
                acc[mt][nt] = __builtin_amdgcn_mfma_f32_16x16x32_bf16(al[mt], bh, acc[mt][nt], 0, 0, 0);
            }
        }
        __syncthreads();
    }

    // epilogue: C/D layout col=lane&15, row=quad*4+reg [m89-verified]
    const bool isL = (wave < 2);
    const int colbase = (wave & 1) * 64;
    const float* bias = isL ? bl : br;
    float* C = isL ? Cl : Cr;
    #pragma unroll
    for (int nt = 0; nt < 4; nt++) {
        const float bv = bias[colbase + nt * 16 + l15];
        #pragma unroll
        for (int mt = 0; mt < 4; mt++) {
            #pragma unroll
            for (int r = 0; r < 4; r++) {
                const int row = row0 + mt * 16 + quad * 4 + r;
                if (row < n)
                    C[(size_t)row * 128 + colbase + nt * 16 + l15] = acc[mt][nt][r] + bv;
            }
        }
    }
}

// ---------------------------------------------------------------- CSR build
__global__ void deg_hist(const int* __restrict__ dst, int* __restrict__ deg) {
    int e = blockIdx.x * 256 + threadIdx.x;
    if (e < N_EDGES) atomicAdd(&deg[dst[e]], 1);
}

__launch_bounds__(SCAN_B)
__global__ void scan_block(const int* __restrict__ deg, int* __restrict__ rowptr,
                           int* __restrict__ btot)
{
    __shared__ int s[SCAN_B];
    const int tid = threadIdx.x;
    const int i = blockIdx.x * SCAN_B + tid;
    int v = (i < N_NODES) ? deg[i] : 0;
    s[tid] = v;
    __syncthreads();
    for (int off = 1; off < SCAN_B; off <<= 1) {
        int t = (tid >= off) ? s[tid - off] : 0;
        __syncthreads();
        s[tid] += t;
        __syncthreads();
    }
    if (i < N_NODES) rowptr[i] = s[tid] - v;
    if (tid == SCAN_B - 1) btot[blockIdx.x] = s[SCAN_B - 1];
}

__global__ void scan_btot(const int* __restrict__ btot, int* __restrict__ boff) {
    if (threadIdx.x == 0) {
        int a = 0;
        for (int b = 0; b < NB; b++) { boff[b] = a; a += btot[b]; }
        boff[NB] = a;
    }
}

__global__ void scan_add(const int* __restrict__ boff, int* __restrict__ rowptr,
                         int* __restrict__ cursor)
{
    int i = blockIdx.x * 256 + threadIdx.x;
    if (i < N_NODES) {
        int r = rowptr[i] + boff[i >> 10];
        rowptr[i] = r;
        cursor[i] = r;
    }
    if (i == N_NODES) rowptr[N_NODES] = boff[NB];
}

__global__ void scatter_csr(const int* __restrict__ src, const int* __restrict__ dst,
                            int* __restrict__ cursor, int* __restrict__ csr_src)
{
    int e = blockIdx.x * 256 + threadIdx.x;
    if (e >= N_EDGES) return;
    int pos = atomicAdd(&cursor[dst[e]], 1);
    csr_src[pos] = src[e];
}

// graph boundaries from sorted batch: gptr[G+1]
__global__ void build_gptr(const int* __restrict__ batch, int* __restrict__ gptr) {
    int i = blockIdx.x * 256 + threadIdx.x;
    if (i > N_NODES) return;
    if (i == 0) {
        for (int g = 0; g <= batch[0]; g++) gptr[g] = 0;
    } else if (i == N_NODES) {
        for (int g = batch[N_NODES - 1] + 1; g <= GG; g++) gptr[g] = N_NODES;
    } else {
        int b0 = batch[i - 1], b1 = batch[i];
        for (int g = b0 + 1; g <= b1; g++) gptr[g] = i;
    }
}

// ------------------------------------------------- fused per-node attention
// one wave per dst node, TWO edges in flight; epilogue emits bf16 hi/lo splits.
__launch_bounds__(256)
__global__ void node_attn(const float* __restrict__ xl, const float* __restrict__ xr,
                          const int* __restrict__ rowptr, const int* __restrict__ csr_src,
                          const float* __restrict__ att, const float* __restrict__ bvec,
                          unsigned short* __restrict__ Hh, unsigned short* __restrict__ Hl)
{
    const int node = (blockIdx.x * 256 + threadIdx.x) >> 6;
    const int lane = threadIdx.x & 63;
    if (node >= N_NODES) return;
    const int half = lane >> 5;
    const int li   = lane & 31;

    const float4 xrd = *(const float4*)(xr + (size_t)node * HD + li * 4);
    const float4 aw  = *(const float4*)(att + li * 4);
    const int beg = rowptr[node];
    const int end = rowptr[node + 1];

    float m = -1e30f, l = 0.f;
    float4 acc = make_float4(0.f, 0.f, 0.f, 0.f);

    int e0 = beg + half;
    int s0 = (e0 < end) ? csr_src[e0] : 0;
    float4 v = *(const float4*)(xl + (size_t)s0 * HD + li * 4);

    for (int base = beg; base < end; base += 2) {
        const bool valid = (base + half) < end;
        float4 vn = v;
        if (base + 2 < end) {
            int e2 = base + 2 + half;
            int s2 = (e2 < end) ? csr_src[e2] : 0;
            vn = *(const float4*)(xl + (size_t)s2 * HD + li * 4);
        }
        float t0 = v.x + xrd.x; t0 = (t0 >= 0.f) ? t0 : NEG_SLOPE * t0;
        float t1 = v.y + xrd.y; t1 = (t1 >= 0.f) ? t1 : NEG_SLOPE * t1;
        float t2 = v.z + xrd.z; t2 = (t2 >= 0.f) ? t2 : NEG_SLOPE * t2;
        float t3 = v.w + xrd.w; t3 = (t3 >= 0.f) ? t3 : NEG_SLOPE * t3;
        float p = t0 * aw.x + t1 * aw.y + t2 * aw.z + t3 * aw.w;
        p += __shfl_xor(p, 1);
        p += __shfl_xor(p, 2);
        p += __shfl_xor(p, 4);
        const float mn = valid ? fmaxf(m, p) : m;
        const float w  = valid ? __expf(p - mn) : 0.f;
        const float sc = __expf(m - mn);
        l = l * sc + w;
        acc.x = acc.x * sc + w * v.x;
        acc.y = acc.y * sc + w * v.y;
        acc.z = acc.z * sc + w * v.z;
        acc.w = acc.w * sc + w * v.w;
        m = mn;
        v = vn;
    }

    const float mo = __shfl_xor(m, 32);
    const float lo = __shfl_xor(l, 32);
    float4 ao;
    ao.x = __shfl_xor(acc.x, 32);
    ao.y = __shfl_xor(acc.y, 32);
    ao.z = __shfl_xor(acc.z, 32);
    ao.w = __shfl_xor(acc.w, 32);
    const float mm = fmaxf(m, mo);
    const float e1 = __expf(m - mm);
    const float e2 = __expf(mo - mm);
    const float ll = l * e1 + lo * e2;
    const float inv = (ll > 0.f) ? 1.f / ll : 0.f;
    const float4 bb = *(const float4*)(bvec + li * 4);
    float o0 = (acc.x * e1 + ao.x * e2) * inv + bb.x;
    float o1 = (acc.y * e1 + ao.y * e2) * inv + bb.y;
    float o2 = (acc.z * e1 + ao.z * e2) * inv + bb.z;
    float o3 = (acc.w * e1 + ao.w * e2) * inv + bb.w;
    o0 = (o0 > 0.f) ? o0 : expm1f(o0);
    o1 = (o1 > 0.f) ? o1 : expm1f(o1);
    o2 = (o2 > 0.f) ? o2 : expm1f(o2);
    o3 = (o3 > 0.f) ? o3 : expm1f(o3);
    if (half == 0) {
        unsigned short h0 = f2bf(o0), h1 = f2bf(o1), h2 = f2bf(o2), h3 = f2bf(o3);
        unsigned short l0 = f2bf(o0 - bf2f(h0)), l1 = f2bf(o1 - bf2f(h1));
        unsigned short l2 = f2bf(o2 - bf2f(h2)), l3 = f2bf(o3 - bf2f(h3));
        *(ushort4*)(Hh + (size_t)node * HD + li * 4) = make_ushort4(h0, h1, h2, h3);
        *(ushort4*)(Hl + (size_t)node * HD + li * 4) = make_ushort4(l0, l1, l2, l3);
    }
}

// ------------------------------------------ fused mean-pool + linear head
// one wave per graph (batch sorted): sums h rows, dots with Wh, scales by 1/cnt.
__launch_bounds__(256)
__global__ void pool_head(const unsigned short* __restrict__ Hh, const unsigned short* __restrict__ Hl,
                          const int* __restrict__ gptr, const float* __restrict__ Wh,
                          const float* __restrict__ bh, float* __restrict__ out)
{
    const int g = (blockIdx.x * 256 + threadIdx.x) >> 6;
    const int lane = threadIdx.x & 63;
    if (g >= GG) return;
    const int b0 = gptr[g], b1 = gptr[g + 1];
    const float2 w = *(const float2*)(Wh + lane * 2);
    float sx = 0.f, sy = 0.f;
    for (int i = b0; i < b1; i++) {
        const unsigned vh = *(const unsigned*)(Hh + (size_t)i * HD + lane * 2);
        const unsigned vl = *(const unsigned*)(Hl + (size_t)i * HD + lane * 2);
        sx += bf2f((unsigned short)(vh & 0xffff)) + bf2f((unsigned short)(vl & 0xffff));
        sy += bf2f((unsigned short)(vh >> 16))    + bf2f((unsigned short)(vl >> 16));
    }
    float d = sx * w.x + sy * w.y;
    d += __shfl_xor(d, 1);
    d += __shfl_xor(d, 2);
    d += __shfl_xor(d, 4);
    d += __shfl_xor(d, 8);
    d += __shfl_xor(d, 16);
    d += __shfl_xor(d, 32);
    if (lane == 0) out[g] = d / fmaxf((float)(b1 - b0), 1.f) + bh[0];
}

// ---------------------------------------------------------------- launch
extern "C" void kernel_launch(void* const* d_in, const int* in_sizes, int n_in,
                              void* d_out, int out_size, void* d_ws, size_t ws_size,
                              hipStream_t stream)
{
    const float* x     = (const float*)d_in[0];
    const int*   edge  = (const int*)d_in[1];
    const int*   batch = (const int*)d_in[2];
    const int*   src   = edge;
    const int*   dst   = edge + N_EDGES;
    const float* Wh    = (const float*)d_in[21];
    const float* bh    = (const float*)d_in[22];
    float* out = (float*)d_out;

    const size_t N128 = (size_t)N_NODES * HD;
    float* buf_xl = (float*)d_ws;                       // N*128 f32
    float* buf_xr = buf_xl + N128;                      // N*128 f32
    unsigned short* Xh  = (unsigned short*)(buf_xr + N128);   // N*128 bf16
    unsigned short* Xl_ = Xh + N128;                    // N*128 bf16
    unsigned short* Wth = Xl_ + N128;                   // 3 * 256*128 bf16
    unsigned short* Wtl = Wth + 3 * 256 * 128;          // 3 * 256*128 bf16
    int* deg     = (int*)(Wtl + 3 * 256 * 128);         // N
    int* rowptr  = deg + N_NODES;                       // N+1
    int* cursor  = rowptr + N_NODES + 1;                // N
    int* csr_src = cursor + N_NODES;                    // E
    int* btot    = csr_src + N_EDGES;                   // NB
    int* boff    = btot + NB;                           // NB+1
    int* gptr    = boff + NB + 1;                       // G+1

    // ---- CSR + graph-boundary build (layer-invariant)
    hipMemsetAsync(deg, 0, (size_t)N_NODES * sizeof(int), stream);
    deg_hist<<<(N_EDGES + 255) / 256, 256, 0, stream>>>(dst, deg);
    scan_block<<<NB, SCAN_B, 0, stream>>>(deg, rowptr, btot);
    scan_btot<<<1, 64, 0, stream>>>(btot, boff);
    scan_add<<<(N_NODES + 256) / 256, 256, 0, stream>>>(boff, rowptr, cursor);
    scatter_csr<<<(N_EDGES + 255) / 256, 256, 0, stream>>>(src, dst, cursor, csr_src);
    build_gptr<<<(N_NODES + 256) / 256, 256, 0, stream>>>(batch, gptr);

    // ---- weight + input split-bf16 conversion
    convert_x<<<(N_NODES * 64 + 255) / 256, 256, 0, stream>>>(x, Xh, Xl_, N_NODES * 64);
    for (int l = 0; l < 3; l++) {
        const int K = (l == 0) ? 64 : 128;
        convert_w<<<(256 * K + 255) / 256, 256, 0, stream>>>(
            (const float*)d_in[3 + 6 * l], (const float*)d_in[5 + 6 * l],
            Wth + l * 256 * 128, Wtl + l * 256 * 128, K);
    }

    const int gemm_grid = (N_NODES + 63) / 64;
    const int attn_grid = (N_NODES + 3) / 4;

    for (int l = 0; l < 3; l++) {
        const float* bl  = (const float*)d_in[4 + 6 * l];
        const float* br  = (const float*)d_in[6 + 6 * l];
        const float* att = (const float*)d_in[7 + 6 * l];
        const float* bb  = (const float*)d_in[8 + 6 * l];

        if (l == 0)
            gemm_mfma<64><<<gemm_grid, 256, 0, stream>>>(Xh, Xl_, Wth, Wtl,
                                                         bl, br, buf_xl, buf_xr, N_NODES);
        else
            gemm_mfma<128><<<gemm_grid, 256, 0, stream>>>(Xh, Xl_,
                                                          Wth + l * 256 * 128, Wtl + l * 256 * 128,
                                                          bl, br, buf_xl, buf_xr, N_NODES);
        node_attn<<<attn_grid, 256, 0, stream>>>(buf_xl, buf_xr, rowptr, csr_src,
                                                 att, bb, Xh, Xl_);
    }

    pool_head<<<GG / 4, 256, 0, stream>>>(Xh, Xl_, gptr, Wh, bh, out);
}

// Round 3
// 516.215 us; speedup vs baseline: 1.0022x; 1.0022x over previous
//
#include <hip/hip_runtime.h>
#include <math.h>

#define N_NODES 50000
#define N_EDGES 800000
#define HD 128          // H*D = 4*32
#define GG 1024
#define NEG_SLOPE 0.2f
#define SCAN_B 1024
#define NB ((N_NODES + SCAN_B - 1) / SCAN_B)   // 49

typedef __attribute__((ext_vector_type(8))) short bf16x8;
typedef __attribute__((ext_vector_type(4))) float f32x4;

__device__ __forceinline__ unsigned short f2bf(float v) {
    unsigned u = __float_as_uint(v);
    u += 0x7fff + ((u >> 16) & 1);       // round-to-nearest-even
    return (unsigned short)(u >> 16);
}
__device__ __forceinline__ float bf2f(unsigned short s) {
    return __uint_as_float((unsigned)s << 16);
}

// --------------------------------------------------- split-bf16 conversions
__global__ void convert_x(const float* __restrict__ x, unsigned short* __restrict__ Xh,
                          unsigned short* __restrict__ Xl, int total)
{
    int i = blockIdx.x * 256 + threadIdx.x;
    if (i >= total) return;
    float v = x[i];
    unsigned short hi = f2bf(v);
    unsigned short lo = f2bf(v - bf2f(hi));   // residual is exact in fp32
    Xh[i] = hi; Xl[i] = lo;
}

// W (K x 128) pair -> Wt (256 x K) transposed, split hi/lo. rows 0..127 = Wl cols.
__global__ void convert_w(const float* __restrict__ Wl, const float* __restrict__ Wr,
                          unsigned short* __restrict__ Wth, unsigned short* __restrict__ Wtl,
                          int K)
{
    int t = blockIdx.x * 256 + threadIdx.x;
    if (t >= 256 * K) return;
    int c = t / K, k = t - c * K;
    float v = (c < 128) ? Wl[(size_t)k * 128 + c] : Wr[(size_t)k * 128 + (c - 128)];
    unsigned short hi = f2bf(v);
    unsigned short lo = f2bf(v - bf2f(hi));
    Wth[t] = hi; Wtl[t] = lo;
}

// --------------------------------------------------- MFMA split-bf16 dual GEMM
template<int K>
__launch_bounds__(256)
__global__ void gemm_mfma(const unsigned short* __restrict__ Xh, const unsigned short* __restrict__ Xl,
                          const unsigned short* __restrict__ Wth, const unsigned short* __restrict__ Wtl,
                          const float* __restrict__ bl, const float* __restrict__ br,
                          float* __restrict__ Cl, float* __restrict__ Cr, int n)
{
    constexpr int KC = 32;
    constexpr int NCH = K / KC;
    constexpr int XR = 40;                     // LDS row stride (elems): 80 B -> 2-way max
    __shared__ unsigned short XsH[64 * XR], XsL[64 * XR];     // 5.12 KB each
    __shared__ unsigned short WsH[256 * XR], WsL[256 * XR];   // 20.5 KB each
    const int tid  = threadIdx.x;
    const int wave = tid >> 6;
    const int lane = tid & 63;
    const int quad = lane >> 4;
    const int l15  = lane & 15;
    const int row0 = blockIdx.x * 64;

    f32x4 acc[4][4];                           // [mt][nt]
    #pragma unroll
    for (int i = 0; i < 4; i++)
        #pragma unroll
        for (int j = 0; j < 4; j++) acc[i][j] = (f32x4){0.f, 0.f, 0.f, 0.f};

    for (int ch = 0; ch < NCH; ch++) {
        const int k0 = ch * KC;
        // stage X chunk: 64 rows x 32 k (1 uint4 per thread per buffer)
        {
            const int r = tid >> 2, seg = tid & 3;
            const int row = row0 + r;
            const size_t go = (size_t)row * K + k0 + seg * 8;
            uint4 vh = make_uint4(0, 0, 0, 0), vl = make_uint4(0, 0, 0, 0);
            if (row < n) { vh = *(const uint4*)(Xh + go); vl = *(const uint4*)(Xl + go); }
            *(uint4*)&XsH[r * XR + seg * 8] = vh;
            *(uint4*)&XsL[r * XR + seg * 8] = vl;
        }
        // stage W chunk: 256 rows x 32 k (4 uint4 per thread per buffer)
        #pragma unroll
        for (int i = 0; i < 4; i++) {
            const int f = tid + i * 256;
            const int wr = f >> 2, seg = f & 3;
            const size_t go = (size_t)wr * K + k0 + seg * 8;
            *(uint4*)&WsH[wr * XR + seg * 8] = *(const uint4*)(Wth + go);
            *(uint4*)&WsL[wr * XR + seg * 8] = *(const uint4*)(Wtl + go);
        }
        __syncthreads();

        bf16x8 ah[4], al[4];
        #pragma unroll
        for (int mt = 0; mt < 4; mt++) {
            ah[mt] = *(const bf16x8*)&XsH[(mt * 16 + l15) * XR + quad * 8];
            al[mt] = *(const bf16x8*)&XsL[(mt * 16 + l15) * XR + quad * 8];
        }
        #pragma unroll
        for (int nt = 0; nt < 4; nt++) {
            const int wr = wave * 64 + nt * 16 + l15;
            const bf16x8 bh = *(const bf16x8*)&WsH[wr * XR + quad * 8];
            const bf16x8 bo = *(const bf16x8*)&WsL[wr * XR + quad * 8];
            #pragma unroll
            for (int mt = 0; mt < 4; mt++) {
                acc[mt][nt] = __builtin_amdgcn_mfma_f32_16x16x32_bf16(ah[mt], bh, acc[mt][nt], 0, 0, 0);
                acc[mt][nt] = __builtin_amdgcn_mfma_f32_16x16x32_bf16(ah[mt], bo, acc[mt][nt], 0, 0, 0);
                acc[mt][nt] = __builtin_amdgcn_mfma_f32_16x16x32_bf16(al[mt], bh, acc[mt][nt], 0, 0, 0);
            }
        }
        __syncthreads();
    }

    // epilogue: C/D layout col=lane&15, row=quad*4+reg [m89-verified]
    const bool isL = (wave < 2);
    const int colbase = (wave & 1) * 64;
    const float* bias = isL ? bl : br;
    float* C = isL ? Cl : Cr;
    #pragma unroll
    for (int nt = 0; nt < 4; nt++) {
        const float bv = bias[colbase + nt * 16 + l15];
        #pragma unroll
        for (int mt = 0; mt < 4; mt++) {
            #pragma unroll
            for (int r = 0; r < 4; r++) {
                const int row = row0 + mt * 16 + quad * 4 + r;
                if (row < n)
                    C[(size_t)row * 128 + colbase + nt * 16 + l15] = acc[mt][nt][r] + bv;
            }
        }
    }
}

// ---------------------------------------------------------------- CSR build
__global__ void deg_hist(const int* __restrict__ dst, int* __restrict__ deg) {
    int e = blockIdx.x * 256 + threadIdx.x;
    if (e < N_EDGES) atomicAdd(&deg[dst[e]], 1);
}

__launch_bounds__(SCAN_B)
__global__ void scan_block(const int* __restrict__ deg, int* __restrict__ rowptr,
                           int* __restrict__ btot)
{
    __shared__ int s[SCAN_B];
    const int tid = threadIdx.x;
    const int i = blockIdx.x * SCAN_B + tid;
    int v = (i < N_NODES) ? deg[i] : 0;
    s[tid] = v;
    __syncthreads();
    for (int off = 1; off < SCAN_B; off <<= 1) {
        int t = (tid >= off) ? s[tid - off] : 0;
        __syncthreads();
        s[tid] += t;
        __syncthreads();
    }
    if (i < N_NODES) rowptr[i] = s[tid] - v;
    if (tid == SCAN_B - 1) btot[blockIdx.x] = s[SCAN_B - 1];
}

__global__ void scan_btot(const int* __restrict__ btot, int* __restrict__ boff) {
    if (threadIdx.x == 0) {
        int a = 0;
        for (int b = 0; b < NB; b++) { boff[b] = a; a += btot[b]; }
        boff[NB] = a;
    }
}

__global__ void scan_add(const int* __restrict__ boff, int* __restrict__ rowptr,
                         int* __restrict__ cursor)
{
    int i = blockIdx.x * 256 + threadIdx.x;
    if (i < N_NODES) {
        int r = rowptr[i] + boff[i >> 10];
        rowptr[i] = r;
        cursor[i] = r;
    }
    if (i == N_NODES) rowptr[N_NODES] = boff[NB];
}

__global__ void scatter_csr(const int* __restrict__ src, const int* __restrict__ dst,
                            int* __restrict__ cursor, int* __restrict__ csr_src)
{
    int e = blockIdx.x * 256 + threadIdx.x;
    if (e >= N_EDGES) return;
    int pos = atomicAdd(&cursor[dst[e]], 1);
    csr_src[pos] = src[e];
}

// graph boundaries from sorted batch: gptr[G+1]
__global__ void build_gptr(const int* __restrict__ batch, int* __restrict__ gptr) {
    int i = blockIdx.x * 256 + threadIdx.x;
    if (i > N_NODES) return;
    if (i == 0) {
        for (int g = 0; g <= batch[0]; g++) gptr[g] = 0;
    } else if (i == N_NODES) {
        for (int g = batch[N_NODES - 1] + 1; g <= GG; g++) gptr[g] = N_NODES;
    } else {
        int b0 = batch[i - 1], b1 = batch[i];
        for (int g = b0 + 1; g <= b1; g++) gptr[g] = i;
    }
}

// ------------------------------------------------- fused per-node attention
// one wave per dst node, FOUR edges in flight (4 groups x 16 lanes, 8 dims/lane).
// PER-HEAD softmax: head = 4-lane cluster (li>>2); score reduce over xor 1,2 ONLY.
// epilogue emits bf16 hi/lo splits.
__launch_bounds__(256)
__global__ void node_attn(const float* __restrict__ xl, const float* __restrict__ xr,
                          const int* __restrict__ rowptr, const int* __restrict__ csr_src,
                          const float* __restrict__ att, const float* __restrict__ bvec,
                          unsigned short* __restrict__ Hh, unsigned short* __restrict__ Hl)
{
    const int node = (blockIdx.x * 256 + threadIdx.x) >> 6;
    const int lane = threadIdx.x & 63;
    if (node >= N_NODES) return;
    const int grp = lane >> 4;     // 4 edge slots
    const int li  = lane & 15;     // 16 lanes per edge, 8 dims each; head = li>>2

    const size_t nb = (size_t)node * HD + li * 8;
    const float4 xr0 = *(const float4*)(xr + nb);
    const float4 xr1 = *(const float4*)(xr + nb + 4);
    const float4 aw0 = *(const float4*)(att + li * 8);
    const float4 aw1 = *(const float4*)(att + li * 8 + 4);
    const int beg = rowptr[node];
    const int end = rowptr[node + 1];

    float m = -1e30f, l = 0.f;
    float4 a0 = make_float4(0.f, 0.f, 0.f, 0.f);
    float4 a1 = make_float4(0.f, 0.f, 0.f, 0.f);

    // prologue gather
    int e0 = beg + grp;
    int s0 = (e0 < end) ? csr_src[e0] : 0;
    float4 v0 = *(const float4*)(xl + (size_t)s0 * HD + li * 8);
    float4 v1 = *(const float4*)(xl + (size_t)s0 * HD + li * 8 + 4);

    for (int base = beg; base < end; base += 4) {
        const bool valid = (base + grp) < end;
        float4 n0 = v0, n1 = v1;
        if (base + 4 < end) {
            const int e2 = base + 4 + grp;
            const int s2 = (e2 < end) ? csr_src[e2] : 0;
            n0 = *(const float4*)(xl + (size_t)s2 * HD + li * 8);
            n1 = *(const float4*)(xl + (size_t)s2 * HD + li * 8 + 4);
        }
        // leaky_relu(v + xr) . att   (8 dims/lane; leaky = max(t, 0.2t))
        float t, p;
        t = v0.x + xr0.x; t = fmaxf(t, NEG_SLOPE * t); p  = t * aw0.x;
        t = v0.y + xr0.y; t = fmaxf(t, NEG_SLOPE * t); p  = fmaf(t, aw0.y, p);
        t = v0.z + xr0.z; t = fmaxf(t, NEG_SLOPE * t); p  = fmaf(t, aw0.z, p);
        t = v0.w + xr0.w; t = fmaxf(t, NEG_SLOPE * t); p  = fmaf(t, aw0.w, p);
        t = v1.x + xr1.x; t = fmaxf(t, NEG_SLOPE * t); p  = fmaf(t, aw1.x, p);
        t = v1.y + xr1.y; t = fmaxf(t, NEG_SLOPE * t); p  = fmaf(t, aw1.y, p);
        t = v1.z + xr1.z; t = fmaxf(t, NEG_SLOPE * t); p  = fmaf(t, aw1.z, p);
        t = v1.w + xr1.w; t = fmaxf(t, NEG_SLOPE * t); p  = fmaf(t, aw1.w, p);
        // per-head score: 4-lane cluster (32 dims) -> xor 1,2 only
        p += __shfl_xor(p, 1);
        p += __shfl_xor(p, 2);

        const float mn = valid ? fmaxf(m, p) : m;
        const float w  = valid ? __expf(p - mn) : 0.f;
        const float sc = __expf(m - mn);
        l = fmaf(l, sc, w);
        a0.x = fmaf(a0.x, sc, w * v0.x);
        a0.y = fmaf(a0.y, sc, w * v0.y);
        a0.z = fmaf(a0.z, sc, w * v0.z);
        a0.w = fmaf(a0.w, sc, w * v0.w);
        a1.x = fmaf(a1.x, sc, w * v1.x);
        a1.y = fmaf(a1.y, sc, w * v1.y);
        a1.z = fmaf(a1.z, sc, w * v1.z);
        a1.w = fmaf(a1.w, sc, w * v1.w);
        m = mn;
        v0 = n0; v1 = n1;
    }

    // cross-group merge (xor 16, then 32): same li (same head/dims), different group
    #pragma unroll
    for (int off = 16; off < 64; off <<= 1) {
        const float mo = __shfl_xor(m, off);
        const float lo = __shfl_xor(l, off);
        float4 b0, b1;
        b0.x = __shfl_xor(a0.x, off); b0.y = __shfl_xor(a0.y, off);
        b0.z = __shfl_xor(a0.z, off); b0.w = __shfl_xor(a0.w, off);
        b1.x = __shfl_xor(a1.x, off); b1.y = __shfl_xor(a1.y, off);
        b1.z = __shfl_xor(a1.z, off); b1.w = __shfl_xor(a1.w, off);
        const float mm = fmaxf(m, mo);
        const float e1 = __expf(m - mm);
        const float e2 = __expf(mo - mm);
        l = l * e1 + lo * e2;
        a0.x = a0.x * e1 + b0.x * e2;
        a0.y = a0.y * e1 + b0.y * e2;
        a0.z = a0.z * e1 + b0.z * e2;
        a0.w = a0.w * e1 + b0.w * e2;
        a1.x = a1.x * e1 + b1.x * e2;
        a1.y = a1.y * e1 + b1.y * e2;
        a1.z = a1.z * e1 + b1.z * e2;
        a1.w = a1.w * e1 + b1.w * e2;
        m = mm;
    }

    if (grp == 0) {
        const float inv = (l > 0.f) ? 1.f / l : 0.f;   // per-head l (per lane)
        const float4 bb0 = *(const float4*)(bvec + li * 8);
        const float4 bb1 = *(const float4*)(bvec + li * 8 + 4);
        float o[8];
        o[0] = fmaf(a0.x, inv, bb0.x);
        o[1] = fmaf(a0.y, inv, bb0.y);
        o[2] = fmaf(a0.z, inv, bb0.z);
        o[3] = fmaf(a0.w, inv, bb0.w);
        o[4] = fmaf(a1.x, inv, bb1.x);
        o[5] = fmaf(a1.y, inv, bb1.y);
        o[6] = fmaf(a1.z, inv, bb1.z);
        o[7] = fmaf(a1.w, inv, bb1.w);
        bf16x8 hv, lv;
        #pragma unroll
        for (int j = 0; j < 8; j++) {
            float e = (o[j] > 0.f) ? o[j] : expm1f(o[j]);
            unsigned short h = f2bf(e);
            hv[j] = (short)h;
            lv[j] = (short)f2bf(e - bf2f(h));
        }
        *(bf16x8*)(Hh + nb) = hv;
        *(bf16x8*)(Hl + nb) = lv;
    }
}

// ------------------------------------------ fused mean-pool + linear head
__launch_bounds__(256)
__global__ void pool_head(const unsigned short* __restrict__ Hh, const unsigned short* __restrict__ Hl,
                          const int* __restrict__ gptr, const float* __restrict__ Wh,
                          const float* __restrict__ bh, float* __restrict__ out)
{
    const int g = (blockIdx.x * 256 + threadIdx.x) >> 6;
    const int lane = threadIdx.x & 63;
    if (g >= GG) return;
    const int b0 = gptr[g], b1 = gptr[g + 1];
    const float2 w = *(const float2*)(Wh + lane * 2);
    float sx = 0.f, sy = 0.f;
    for (int i = b0; i < b1; i++) {
        const unsigned vh = *(const unsigned*)(Hh + (size_t)i * HD + lane * 2);
        const unsigned vl = *(const unsigned*)(Hl + (size_t)i * HD + lane * 2);
        sx += bf2f((unsigned short)(vh & 0xffff)) + bf2f((unsigned short)(vl & 0xffff));
        sy += bf2f((unsigned short)(vh >> 16))    + bf2f((unsigned short)(vl >> 16));
    }
    float d = sx * w.x + sy * w.y;
    d += __shfl_xor(d, 1);
    d += __shfl_xor(d, 2);
    d += __shfl_xor(d, 4);
    d += __shfl_xor(d, 8);
    d += __shfl_xor(d, 16);
    d += __shfl_xor(d, 32);
    if (lane == 0) out[g] = d / fmaxf((float)(b1 - b0), 1.f) + bh[0];
}

// ---------------------------------------------------------------- launch
extern "C" void kernel_launch(void* const* d_in, const int* in_sizes, int n_in,
                              void* d_out, int out_size, void* d_ws, size_t ws_size,
                              hipStream_t stream)
{
    const float* x     = (const float*)d_in[0];
    const int*   edge  = (const int*)d_in[1];
    const int*   batch = (const int*)d_in[2];
    const int*   src   = edge;
    const int*   dst   = edge + N_EDGES;
    const float* Wh    = (const float*)d_in[21];
    const float* bh    = (const float*)d_in[22];
    float* out = (float*)d_out;

    const size_t N128 = (size_t)N_NODES * HD;
    float* buf_xl = (float*)d_ws;                       // N*128 f32
    float* buf_xr = buf_xl + N128;                      // N*128 f32
    unsigned short* Xh  = (unsigned short*)(buf_xr + N128);   // N*128 bf16
    unsigned short* Xl_ = Xh + N128;                    // N*128 bf16
    unsigned short* Wth = Xl_ + N128;                   // 3 * 256*128 bf16
    unsigned short* Wtl = Wth + 3 * 256 * 128;          // 3 * 256*128 bf16
    int* deg     = (int*)(Wtl + 3 * 256 * 128);         // N
    int* rowptr  = deg + N_NODES;                       // N+1
    int* cursor  = rowptr + N_NODES + 1;                // N
    int* csr_src = cursor + N_NODES;                    // E
    int* btot    = csr_src + N_EDGES;                   // NB
    int* boff    = btot + NB;                           // NB+1
    int* gptr    = boff + NB + 1;                       // G+1

    // ---- CSR + graph-boundary build (layer-invariant)
    hipMemsetAsync(deg, 0, (size_t)N_NODES * sizeof(int), stream);
    deg_hist<<<(N_EDGES + 255) / 256, 256, 0, stream>>>(dst, deg);
    scan_block<<<NB, SCAN_B, 0, stream>>>(deg, rowptr, btot);
    scan_btot<<<1, 64, 0, stream>>>(btot, boff);
    scan_add<<<(N_NODES + 256) / 256, 256, 0, stream>>>(boff, rowptr, cursor);
    scatter_csr<<<(N_EDGES + 255) / 256, 256, 0, stream>>>(src, dst, cursor, csr_src);
    build_gptr<<<(N_NODES + 256) / 256, 256, 0, stream>>>(batch, gptr);

    // ---- weight + input split-bf16 conversion
    convert_x<<<(N_NODES * 64 + 255) / 256, 256, 0, stream>>>(x, Xh, Xl_, N_NODES * 64);
    for (int l = 0; l < 3; l++) {
        const int K = (l == 0) ? 64 : 128;
        convert_w<<<(256 * K + 255) / 256, 256, 0, stream>>>(
            (const float*)d_in[3 + 6 * l], (const float*)d_in[5 + 6 * l],
            Wth + l * 256 * 128, Wtl + l * 256 * 128, K);
    }

    const int gemm_grid = (N_NODES + 63) / 64;
    const int attn_grid = (N_NODES + 3) / 4;

    for (int l = 0; l < 3; l++) {
        const float* bl  = (const float*)d_in[4 + 6 * l];
        const float* br  = (const float*)d_in[6 + 6 * l];
        const float* att = (const float*)d_in[7 + 6 * l];
        const float* bb  = (const float*)d_in[8 + 6 * l];

        if (l == 0)
            gemm_mfma<64><<<gemm_grid, 256, 0, stream>>>(Xh, Xl_, Wth, Wtl,
                                                         bl, br, buf_xl, buf_xr, N_NODES);
        else
            gemm_mfma<128><<<gemm_grid, 256, 0, stream>>>(Xh, Xl_,
                                                          Wth + l * 256 * 128, Wtl + l * 256 * 128,
                                                          bl, br, buf_xl, buf_xr, N_NODES);
        node_attn<<<attn_grid, 256, 0, stream>>>(buf_xl, buf_xr, rowptr, csr_src,
                                                 att, bb, Xh, Xl_);
    }

    pool_head<<<GG / 4, 256, 0, stream>>>(Xh, Xl_, gptr, Wh, bh, out);
}